// Round 1
// baseline (462.529 us; speedup 1.0000x reference)
//
#include <hip/hip_runtime.h>

#define D_FEAT 64
#define MAX_K 8

// Kernel 1: combined[n][d] = sum_k max(w_k,0) * h_ops[k][n][d]
// Pure streaming, float4-vectorized, grid-stride.
__global__ __launch_bounds__(256) void combine_kernel(
    const float* __restrict__ h_ops,
    const float* __restrict__ weights,
    float* __restrict__ combined,
    int total4, int K) {
    float w[MAX_K];
    for (int k = 0; k < K; ++k) {
        float wk = weights[k];
        w[k] = wk > 0.f ? wk : 0.f;
    }
    int stride = gridDim.x * blockDim.x;
    for (int i = blockIdx.x * blockDim.x + threadIdx.x; i < total4; i += stride) {
        float4 acc = make_float4(0.f, 0.f, 0.f, 0.f);
        for (int k = 0; k < K; ++k) {
            float4 v = reinterpret_cast<const float4*>(h_ops)[(size_t)k * total4 + i];
            acc.x = fmaf(w[k], v.x, acc.x);
            acc.y = fmaf(w[k], v.y, acc.y);
            acc.z = fmaf(w[k], v.z, acc.z);
            acc.w = fmaf(w[k], v.w, acc.w);
        }
        reinterpret_cast<float4*>(combined)[i] = acc;
    }
}

// Kernel 2: one wave (64 lanes) per output node; lane = feature index.
// row[] is sorted -> segment located via binary search, no atomics.
__global__ __launch_bounds__(256) void spmm_kernel(
    const float* __restrict__ combined,
    const float* __restrict__ vals,
    const int* __restrict__ row,
    const int* __restrict__ col,
    const float* __restrict__ weights,
    float* __restrict__ out,
    int n_nodes, int n_edges, int K) {
    int wid = (blockIdx.x * blockDim.x + threadIdx.x) >> 6;
    int lane = threadIdx.x & 63;
    if (wid >= n_nodes) return;

    // lower_bound(row, wid)
    int lo = 0, hi = n_edges;
    while (lo < hi) { int mid = (lo + hi) >> 1; if (row[mid] < wid) lo = mid + 1; else hi = mid; }
    int start = lo;
    // upper_bound(row, wid)
    hi = n_edges;
    while (lo < hi) { int mid = (lo + hi) >> 1; if (row[mid] <= wid) lo = mid + 1; else hi = mid; }
    int end = lo;

    float acc = 0.f;
    for (int e = start; e < end; ++e) {
        int c = col[e];        // broadcast load (all lanes same addr)
        float v = vals[e];     // broadcast load
        acc = fmaf(v, combined[(size_t)c * D_FEAT + lane], acc);  // coalesced 256B
    }

    float s = 0.f;
    for (int k = 0; k < K; ++k) {
        float wk = weights[k];
        if (!(wk > 0.f)) s += wk;
    }
    out[(size_t)wid * D_FEAT + lane] = acc + s;
}

// Fallback if workspace is too small: recompute combined on-the-fly per edge.
__global__ __launch_bounds__(256) void spmm_fused_kernel(
    const float* __restrict__ h_ops,
    const float* __restrict__ vals,
    const int* __restrict__ row,
    const int* __restrict__ col,
    const float* __restrict__ weights,
    float* __restrict__ out,
    int n_nodes, int n_edges, int K, size_t plane) {
    int wid = (blockIdx.x * blockDim.x + threadIdx.x) >> 6;
    int lane = threadIdx.x & 63;
    if (wid >= n_nodes) return;

    float w[MAX_K];
    for (int k = 0; k < K; ++k) {
        float wk = weights[k];
        w[k] = wk > 0.f ? wk : 0.f;
    }

    int lo = 0, hi = n_edges;
    while (lo < hi) { int mid = (lo + hi) >> 1; if (row[mid] < wid) lo = mid + 1; else hi = mid; }
    int start = lo;
    hi = n_edges;
    while (lo < hi) { int mid = (lo + hi) >> 1; if (row[mid] <= wid) lo = mid + 1; else hi = mid; }
    int end = lo;

    float acc = 0.f;
    for (int e = start; e < end; ++e) {
        int c = col[e];
        float v = vals[e];
        float comb = 0.f;
        for (int k = 0; k < K; ++k) {
            comb = fmaf(w[k], h_ops[(size_t)k * plane + (size_t)c * D_FEAT + lane], comb);
        }
        acc = fmaf(v, comb, acc);
    }

    float s = 0.f;
    for (int k = 0; k < K; ++k) {
        float wk = weights[k];
        if (!(wk > 0.f)) s += wk;
    }
    out[(size_t)wid * D_FEAT + lane] = acc + s;
}

extern "C" void kernel_launch(void* const* d_in, const int* in_sizes, int n_in,
                              void* d_out, int out_size, void* d_ws, size_t ws_size,
                              hipStream_t stream) {
    const float* h_ops   = (const float*)d_in[0];
    const float* weights = (const float*)d_in[1];
    const float* vals    = (const float*)d_in[2];
    const int*   row     = (const int*)d_in[3];
    const int*   col     = (const int*)d_in[4];
    float* out = (float*)d_out;

    int K = in_sizes[1];
    if (K > MAX_K) K = MAX_K;
    int E = in_sizes[2];
    int N = out_size / D_FEAT;
    int total = N * D_FEAT;
    size_t need = (size_t)total * sizeof(float);

    int spmm_blocks = (N * 64 + 255) / 256;  // 4 nodes (waves) per 256-thread block

    if (ws_size >= need) {
        float* combined = (float*)d_ws;
        int total4 = total / 4;
        combine_kernel<<<2048, 256, 0, stream>>>(h_ops, weights, combined, total4, K);
        spmm_kernel<<<spmm_blocks, 256, 0, stream>>>(combined, vals, row, col, weights,
                                                     out, N, E, K);
    } else {
        spmm_fused_kernel<<<spmm_blocks, 256, 0, stream>>>(h_ops, vals, row, col, weights,
                                                           out, N, E, K, (size_t)total);
    }
}

// Round 2
// 149.958 us; speedup vs baseline: 3.0844x; 3.0844x over previous
//
#include <hip/hip_runtime.h>

#define D_FEAT 64
#define MAX_K 8

// Kernel 1: combined[n][d] = sum_k max(w_k,0) * h_ops[k][n][d]
__global__ __launch_bounds__(256) void combine_kernel(
    const float* __restrict__ h_ops,
    const float* __restrict__ weights,
    float* __restrict__ combined,
    int total4, int K) {
    float w[MAX_K];
    for (int k = 0; k < K; ++k) {
        float wk = weights[k];
        w[k] = wk > 0.f ? wk : 0.f;
    }
    int stride = gridDim.x * blockDim.x;
    for (int i = blockIdx.x * blockDim.x + threadIdx.x; i < total4; i += stride) {
        float4 acc = make_float4(0.f, 0.f, 0.f, 0.f);
        for (int k = 0; k < K; ++k) {
            float4 v = reinterpret_cast<const float4*>(h_ops)[(size_t)k * total4 + i];
            acc.x = fmaf(w[k], v.x, acc.x);
            acc.y = fmaf(w[k], v.y, acc.y);
            acc.z = fmaf(w[k], v.z, acc.z);
            acc.w = fmaf(w[k], v.w, acc.w);
        }
        reinterpret_cast<float4*>(combined)[i] = acc;
    }
}

// Kernel 1b: CSR row_ptr from sorted row[] (edge-parallel, gaps filled).
__global__ __launch_bounds__(256) void build_rowptr_kernel(
    const int* __restrict__ row, int* __restrict__ row_ptr, int E, int N) {
    int stride = gridDim.x * blockDim.x;
    for (int e = blockIdx.x * blockDim.x + threadIdx.x; e < E; e += stride) {
        int r = row[e];
        int rp = (e == 0) ? -1 : row[e - 1];
        for (int x = rp + 1; x <= r; ++x) row_ptr[x] = e;
        if (e == E - 1) {
            for (int x = r + 1; x <= N; ++x) row_ptr[x] = E;
        }
    }
}

// Kernel 2: one wave per node, lane = feature. row_ptr removes binary search;
// 8-deep manual unroll keeps 8 independent gathers in flight per wave.
__global__ __launch_bounds__(256) void spmm_kernel_rp(
    const float* __restrict__ combined,
    const float* __restrict__ vals,
    const int* __restrict__ row_ptr,
    const int* __restrict__ col,
    const float* __restrict__ weights,
    float* __restrict__ out,
    int n_nodes, int K) {
    int wid = (blockIdx.x * blockDim.x + threadIdx.x) >> 6;
    int lane = threadIdx.x & 63;
    if (wid >= n_nodes) return;

    int start = row_ptr[wid];
    int end = row_ptr[wid + 1];

    float acc = 0.f;
    int e = start;
    int main_end = start + ((end - start) & ~7);
    for (; e < main_end; e += 8) {
        int   c0 = col[e + 0], c1 = col[e + 1], c2 = col[e + 2], c3 = col[e + 3];
        int   c4 = col[e + 4], c5 = col[e + 5], c6 = col[e + 6], c7 = col[e + 7];
        float v0 = vals[e + 0], v1 = vals[e + 1], v2 = vals[e + 2], v3 = vals[e + 3];
        float v4 = vals[e + 4], v5 = vals[e + 5], v6 = vals[e + 6], v7 = vals[e + 7];
        float g0 = combined[(size_t)c0 * D_FEAT + lane];
        float g1 = combined[(size_t)c1 * D_FEAT + lane];
        float g2 = combined[(size_t)c2 * D_FEAT + lane];
        float g3 = combined[(size_t)c3 * D_FEAT + lane];
        float g4 = combined[(size_t)c4 * D_FEAT + lane];
        float g5 = combined[(size_t)c5 * D_FEAT + lane];
        float g6 = combined[(size_t)c6 * D_FEAT + lane];
        float g7 = combined[(size_t)c7 * D_FEAT + lane];
        acc = fmaf(v0, g0, acc); acc = fmaf(v1, g1, acc);
        acc = fmaf(v2, g2, acc); acc = fmaf(v3, g3, acc);
        acc = fmaf(v4, g4, acc); acc = fmaf(v5, g5, acc);
        acc = fmaf(v6, g6, acc); acc = fmaf(v7, g7, acc);
    }
    for (; e < end; ++e) {
        acc = fmaf(vals[e], combined[(size_t)col[e] * D_FEAT + lane], acc);
    }

    float s = 0.f;
    for (int k = 0; k < K; ++k) {
        float wk = weights[k];
        if (!(wk > 0.f)) s += wk;
    }
    out[(size_t)wid * D_FEAT + lane] = acc + s;
}

// Fallback: binary-search variant (no row_ptr workspace).
__global__ __launch_bounds__(256) void spmm_kernel_bs(
    const float* __restrict__ combined,
    const float* __restrict__ vals,
    const int* __restrict__ row,
    const int* __restrict__ col,
    const float* __restrict__ weights,
    float* __restrict__ out,
    int n_nodes, int n_edges, int K) {
    int wid = (blockIdx.x * blockDim.x + threadIdx.x) >> 6;
    int lane = threadIdx.x & 63;
    if (wid >= n_nodes) return;

    int lo = 0, hi = n_edges;
    while (lo < hi) { int mid = (lo + hi) >> 1; if (row[mid] < wid) lo = mid + 1; else hi = mid; }
    int start = lo;
    hi = n_edges;
    while (lo < hi) { int mid = (lo + hi) >> 1; if (row[mid] <= wid) lo = mid + 1; else hi = mid; }
    int end = lo;

    float acc = 0.f;
    for (int e = start; e < end; ++e) {
        acc = fmaf(vals[e], combined[(size_t)col[e] * D_FEAT + lane], acc);
    }
    float s = 0.f;
    for (int k = 0; k < K; ++k) {
        float wk = weights[k];
        if (!(wk > 0.f)) s += wk;
    }
    out[(size_t)wid * D_FEAT + lane] = acc + s;
}

// Last-resort fallback: recompute combined per edge (tiny workspace).
__global__ __launch_bounds__(256) void spmm_fused_kernel(
    const float* __restrict__ h_ops,
    const float* __restrict__ vals,
    const int* __restrict__ row,
    const int* __restrict__ col,
    const float* __restrict__ weights,
    float* __restrict__ out,
    int n_nodes, int n_edges, int K, size_t plane) {
    int wid = (blockIdx.x * blockDim.x + threadIdx.x) >> 6;
    int lane = threadIdx.x & 63;
    if (wid >= n_nodes) return;

    float w[MAX_K];
    for (int k = 0; k < K; ++k) {
        float wk = weights[k];
        w[k] = wk > 0.f ? wk : 0.f;
    }
    int lo = 0, hi = n_edges;
    while (lo < hi) { int mid = (lo + hi) >> 1; if (row[mid] < wid) lo = mid + 1; else hi = mid; }
    int start = lo;
    hi = n_edges;
    while (lo < hi) { int mid = (lo + hi) >> 1; if (row[mid] <= wid) lo = mid + 1; else hi = mid; }
    int end = lo;

    float acc = 0.f;
    for (int e = start; e < end; ++e) {
        int c = col[e];
        float v = vals[e];
        float comb = 0.f;
        for (int k = 0; k < K; ++k) {
            comb = fmaf(w[k], h_ops[(size_t)k * plane + (size_t)c * D_FEAT + lane], comb);
        }
        acc = fmaf(v, comb, acc);
    }
    float s = 0.f;
    for (int k = 0; k < K; ++k) {
        float wk = weights[k];
        if (!(wk > 0.f)) s += wk;
    }
    out[(size_t)wid * D_FEAT + lane] = acc + s;
}

extern "C" void kernel_launch(void* const* d_in, const int* in_sizes, int n_in,
                              void* d_out, int out_size, void* d_ws, size_t ws_size,
                              hipStream_t stream) {
    const float* h_ops   = (const float*)d_in[0];
    const float* weights = (const float*)d_in[1];
    const float* vals    = (const float*)d_in[2];
    const int*   row     = (const int*)d_in[3];
    const int*   col     = (const int*)d_in[4];
    float* out = (float*)d_out;

    int K = in_sizes[1];
    if (K > MAX_K) K = MAX_K;
    int E = in_sizes[2];
    int N = out_size / D_FEAT;
    int total = N * D_FEAT;
    size_t need_combined = (size_t)total * sizeof(float);
    size_t need_rowptr   = (size_t)(N + 1) * sizeof(int);

    int spmm_blocks = (N * 64 + 255) / 256;  // 4 waves (nodes) per block

    if (ws_size >= need_combined + need_rowptr) {
        float* combined = (float*)d_ws;
        int*   row_ptr  = (int*)((char*)d_ws + need_combined);
        int total4 = total / 4;
        combine_kernel<<<2048, 256, 0, stream>>>(h_ops, weights, combined, total4, K);
        build_rowptr_kernel<<<2048, 256, 0, stream>>>(row, row_ptr, E, N);
        spmm_kernel_rp<<<spmm_blocks, 256, 0, stream>>>(combined, vals, row_ptr, col,
                                                        weights, out, N, K);
    } else if (ws_size >= need_combined) {
        float* combined = (float*)d_ws;
        int total4 = total / 4;
        combine_kernel<<<2048, 256, 0, stream>>>(h_ops, weights, combined, total4, K);
        spmm_kernel_bs<<<spmm_blocks, 256, 0, stream>>>(combined, vals, row, col,
                                                        weights, out, N, E, K);
    } else {
        spmm_fused_kernel<<<spmm_blocks, 256, 0, stream>>>(h_ops, vals, row, col, weights,
                                                           out, N, E, K, (size_t)total);
    }
}